// Round 8
// baseline (419.240 us; speedup 1.0000x reference)
//
#include <hip/hip_runtime.h>
#include <math.h>

constexpr int N_NODES = 50000;
constexpr int N_PAD   = 50048;    // 391 * 128, padded rows for tile overrun
constexpr int N_EDGES = 400000;
constexpr int IN_F = 512;
constexpr int HEADS = 8;
constexpr int OUT_F = 64;
constexpr int HF = 512;           // HEADS * OUT_F
constexpr float NEG = 0.2f;

typedef __bf16 bf16x8 __attribute__((ext_vector_type(8)));
typedef float  f32x4  __attribute__((ext_vector_type(4)));

__device__ __forceinline__ unsigned short f2bf(float f) {
    unsigned u = __float_as_uint(f);
    u += 0x7fffu + ((u >> 16) & 1u);   // round-to-nearest-even (inputs finite)
    return (unsigned short)(u >> 16);
}
__device__ __forceinline__ unsigned packbf2(float lo, float hi) {
    return (unsigned)f2bf(lo) | ((unsigned)f2bf(hi) << 16);
}

// ---------------------------------------------------------------------------
// K14: merged dispatch — [0,256): W_val transpose->bf16; [256,289): fold
// attention vectors into w_lr (bf16, [16 cols][512 k], col<8 = l-side heads,
// col>=8 = r-side) + c_lr[16] (bias dots); [289,...): dst-degree histogram.
// (deg zeroed by memset.)
// ---------------------------------------------------------------------------
constexpr int K14_HIST0 = 289;
constexpr int K14_BLOCKS = K14_HIST0 + (N_EDGES + 255) / 256;   // 289 + 1563

__global__ __launch_bounds__(256) void k14_misc(
        const float* __restrict__ W_val, unsigned short* __restrict__ Wt,
        const float* __restrict__ W_src, const float* __restrict__ b_src,
        const float* __restrict__ W_dst, const float* __restrict__ b_dst,
        const float* __restrict__ attn_l, const float* __restrict__ attn_r,
        unsigned short* __restrict__ w_lr, float* __restrict__ c_lr,
        const int* __restrict__ dst, int* __restrict__ deg) {
    __shared__ float tile[32][33];
    int b = blockIdx.x, t = threadIdx.x;
    if (b < 256) {
        int bi = b >> 4, bj = b & 15;
        for (int i = t; i < 1024; i += 256) {
            int r = i >> 5, c = i & 31;
            tile[r][c] = W_val[(size_t)(bi * 32 + r) * HF + bj * 32 + c];
        }
        __syncthreads();
        for (int i = t; i < 1024; i += 256) {
            int r = i >> 5, c = i & 31;
            Wt[(size_t)(bj * 32 + r) * IN_F + bi * 32 + c] = f2bf(tile[c][r]);
        }
    } else if (b < K14_HIST0) {
        int gid = (b - 256) * 256 + t;
        if (gid < 4096) {
            int k = gid >> 3, h = gid & 7;
            float s = 0.f;
            #pragma unroll 8
            for (int f = 0; f < OUT_F; ++f) s += W_src[k * HF + h * OUT_F + f] * attn_l[h * OUT_F + f];
            w_lr[h * IN_F + k] = f2bf(s);
        } else if (gid < 8192) {
            int g = gid - 4096;
            int k = g >> 3, h = g & 7;
            float s = 0.f;
            #pragma unroll 8
            for (int f = 0; f < OUT_F; ++f) s += W_dst[k * HF + h * OUT_F + f] * attn_r[h * OUT_F + f];
            w_lr[(8 + h) * IN_F + k] = f2bf(s);
        } else if (gid < 8192 + 16) {
            int g = gid - 8192;
            int h = g & 7;
            float s = 0.f;
            if (g < 8) {
                for (int f = 0; f < OUT_F; ++f) s += b_src[h * OUT_F + f] * attn_l[h * OUT_F + f];
                c_lr[h] = s;
            } else {
                for (int f = 0; f < OUT_F; ++f) s += b_dst[h * OUT_F + f] * attn_r[h * OUT_F + f];
                c_lr[8 + h] = s;
            }
        }
    } else {
        int e = (b - K14_HIST0) * 256 + t;
        if (e < N_EDGES) atomicAdd(&deg[dst[e]], 1);
    }
}

// ---------------------------------------------------------------------------
// KS: single-dispatch exclusive scan (redundant-prefix per block, no serial).
// ---------------------------------------------------------------------------
__global__ __launch_bounds__(1024) void kS_scan(const int* __restrict__ deg,
                                                int* __restrict__ offs,
                                                int* __restrict__ cursor) {
    __shared__ int wsum[16];
    __shared__ int base_s;
    int b = blockIdx.x, t = threadIdx.x;
    int lane = t & 63, wid = t >> 6;

    int pre = 0;
    for (int i = t; i < b * 1024; i += 1024) pre += deg[i];
    #pragma unroll
    for (int off = 32; off; off >>= 1) pre += __shfl_down(pre, (unsigned)off, 64);
    if (lane == 0) wsum[wid] = pre;
    __syncthreads();
    if (t == 0) {
        int s = 0;
        for (int i = 0; i < 16; ++i) s += wsum[i];
        base_s = s;
    }
    __syncthreads();
    int base = base_s;
    __syncthreads();

    int i = b * 1024 + t;
    int v = (i < N_NODES) ? deg[i] : 0;
    int x = v;
    #pragma unroll
    for (int off = 1; off < 64; off <<= 1) {
        int y = __shfl_up(x, (unsigned)off, 64);
        if (lane >= off) x += y;
    }
    if (lane == 63) wsum[wid] = x;
    __syncthreads();
    if (wid == 0) {
        int s = (lane < 16) ? wsum[lane] : 0;
        #pragma unroll
        for (int off = 1; off < 16; off <<= 1) {
            int y = __shfl_up(s, (unsigned)off, 64);
            if (lane >= off) s += y;
        }
        if (lane < 16) wsum[lane] = s;
    }
    __syncthreads();
    int woff = wid ? wsum[wid - 1] : 0;
    if (i < N_NODES) {
        int excl = base + woff + x - v;
        offs[i] = excl;
        cursor[i] = excl;
    }
}

// ---------------------------------------------------------------------------
// K36 (R7): mega-dispatch = GEMM (A direct-from-global) + edge scatter.
// GEMM blocks [0,1568): A-reuse within a block is only 2x (wn pair), so A is
// NOT staged in LDS at all — each wave loads its fp32 A fragments straight
// from feat (XCD-pinned -> panel L2-resident after first touch) and converts
// in-register via compiler __bf16 casts (RNE, = f2bf). This removes the
// R6 LOADA/WRITEA serial chain and halves LDS to 32 KB (B dbuf only) ->
// 4-5 blocks/CU by LDS (R6: 2), ONE barrier per K-step whose vmcnt drain
// (B of k+1) is covered by the full MFMA+A-load phase.
// el/er computed as a 16-col MFMA strip (bn==0,wn==0 waves), R5-validated.
// Blocks [1568,...): counting-sort scatter (independent, co-resident).
// ---------------------------------------------------------------------------
constexpr int K3_GEMM = 8 * 49 * 4;                         // 1568 (4 dummies)
constexpr int K36_BLOCKS = K3_GEMM + (N_EDGES + 255) / 256; // + 1563

__global__ __launch_bounds__(256) void k36_gemm_scatter(
        const float* __restrict__ feat,
        const unsigned short* __restrict__ Bbf,     // Wt [512 cols][512 k]
        const unsigned short* __restrict__ w_lr,    // [16][512] bf16
        const float* __restrict__ c_lr,             // [16]
        const float* __restrict__ bias,
        unsigned short* __restrict__ C,             // feat_v [N_PAD][512]
        float* __restrict__ el, float* __restrict__ er,
        const int* __restrict__ src, const int* __restrict__ dst,
        int* __restrict__ cursor, int* __restrict__ srcs) {
    __shared__ unsigned short Bs[2][128 * 64];      // 32 KB total

    int b = blockIdx.x;
    if (b >= K3_GEMM) {                   // -------- scatter path (was k6)
        int e = (b - K3_GEMM) * 256 + threadIdx.x;
        if (e < N_EDGES) {
            int pos = atomicAdd(&cursor[dst[e]], 1);
            srcs[pos] = src[e];
        }
        return;
    }

    // -------- GEMM path: XCD-pinned tile mapping (4 bn of a bm -> one XCD)
    int xcd = b & 7;
    int r0 = b >> 3;                      // 0..195
    int bn = r0 & 3;
    int bm = xcd + 8 * (r0 >> 2);         // bmg 0..48
    if (bm >= N_PAD / 128) return;        // 391 bms; 4 dummy blocks exit

    int tid = threadIdx.x;
    int w = tid >> 6, lane = tid & 63;
    int rowBase = bm * 128, colBase = bn * 128;
    int wm = w >> 1, wn = w & 1;
    int c15 = lane & 15, q = lane >> 4;
    bool doE = (bn == 0) && (wn == 0);    // el/er strip owner

    // per-lane A row pointers (clamped for pad rows; feat is not padded)
    const float* aptr[4];
    #pragma unroll
    for (int mi = 0; mi < 4; ++mi) {
        int r = rowBase + wm * 64 + mi * 16 + c15;
        if (r > N_NODES - 1) r = N_NODES - 1;
        aptr[mi] = feat + (size_t)r * IN_F;
    }

    f32x4 acc[4][4] = {};
    f32x4 accE[4] = {};
    int e0 = w * 256 + lane;              // B staging slot base (+ rnd*64)

    auto ISSUEB = [&](int k0, int buf) {
        #pragma unroll
        for (int rnd = 0; rnd < 4; ++rnd) {
            int e = e0 + rnd * 64;
            int r = e >> 3, p = e & 7;
            int lc = p ^ (r & 7);         // XOR chunk swizzle (matches reads)
            const unsigned short* g = Bbf + (size_t)(colBase + r) * IN_F + k0 + lc * 8;
            __builtin_amdgcn_global_load_lds(
                (const __attribute__((address_space(1))) unsigned int*)g,
                (__attribute__((address_space(3))) unsigned int*)&Bs[buf][e * 8],
                16, 0, 0);
        }
    };

    ISSUEB(0, 0);
    __syncthreads();                      // B(0) resident

    for (int k0 = 0; k0 < IN_F; k0 += 64) {
        int cur = (k0 >> 6) & 1, nxt = cur ^ 1;
        if (k0 + 64 < IN_F) ISSUEB(k0 + 64, nxt);   // in flight across phase

        #pragma unroll
        for (int ks = 0; ks < 2; ++ks) {
            bf16x8 a[4], bb[4];
            #pragma unroll
            for (int mi = 0; mi < 4; ++mi) {
                const float* g = aptr[mi] + k0 + ks * 32 + q * 8;
                float4 fa = *(const float4*)g;
                float4 fb = *(const float4*)(g + 4);
                bf16x8 t;
                t[0] = (__bf16)fa.x; t[1] = (__bf16)fa.y;
                t[2] = (__bf16)fa.z; t[3] = (__bf16)fa.w;
                t[4] = (__bf16)fb.x; t[5] = (__bf16)fb.y;
                t[6] = (__bf16)fb.z; t[7] = (__bf16)fb.w;
                a[mi] = t;
            }
            #pragma unroll
            for (int nj = 0; nj < 4; ++nj) {
                int row = wn * 64 + nj * 16 + c15;
                int pc = (ks * 4 + q) ^ (row & 7);
                bb[nj] = *(const bf16x8*)&Bs[cur][row * 64 + pc * 8];
            }
            #pragma unroll
            for (int mi = 0; mi < 4; ++mi)
                #pragma unroll
                for (int nj = 0; nj < 4; ++nj)
                    acc[mi][nj] = __builtin_amdgcn_mfma_f32_16x16x32_bf16(
                        a[mi], bb[nj], acc[mi][nj], 0, 0, 0);
            if (doE) {
                bf16x8 be = *(const bf16x8*)(w_lr + (size_t)c15 * IN_F + k0 + ks * 32 + q * 8);
                #pragma unroll
                for (int mi = 0; mi < 4; ++mi)
                    accE[mi] = __builtin_amdgcn_mfma_f32_16x16x32_bf16(
                        a[mi], be, accE[mi], 0, 0, 0);
            }
        }
        __syncthreads();                  // drains B(k+1); covered by phase
    }

    #pragma unroll
    for (int nj = 0; nj < 4; ++nj) {
        int col = colBase + wn * 64 + nj * 16 + c15;
        float bv = bias[col];
        #pragma unroll
        for (int mi = 0; mi < 4; ++mi) {
            int row0 = rowBase + wm * 64 + mi * 16 + q * 4;
            #pragma unroll
            for (int rg = 0; rg < 4; ++rg) {
                C[(size_t)(row0 + rg) * HF + col] = f2bf(acc[mi][nj][rg] + bv);
            }
        }
    }

    if (doE) {
        float cadd = c_lr[c15];
        int side = c15 >> 3, hh = c15 & 7;
        #pragma unroll
        for (int mi = 0; mi < 4; ++mi) {
            int row0 = rowBase + wm * 64 + mi * 16 + q * 4;
            #pragma unroll
            for (int rg = 0; rg < 4; ++rg) {
                float v = accE[mi][rg] + cadd;
                if (side) er[(size_t)(row0 + rg) * 8 + hh] = v;
                else      el[(size_t)(row0 + rg) * 8 + hh] = v;
            }
        }
    }
}

// ---------------------------------------------------------------------------
// K8: fused edge-softmax + aggregation — EXACT R0 form (77.4 µs measured,
// the best of 4 structural variants). One WAVE per node; lane owns a 16B
// uint4 chunk (8 bf16 feats, one head = lane>>3). 16B/lane gather is the
// instruction-efficiency sweet spot (2B/lane: 8x VMEM instrs, 2.3x time).
// No min-waves hint (forcing 8/EU spilled acc[] -> 375 MB scratch, 2.3x).
// Persistent/chunked grids measured neutral-to-worse; 4.0-4.2 TB/s L2-fill
// is this gather pattern's service floor. Atomic-free.
// ---------------------------------------------------------------------------
__device__ __forceinline__ void accum8(float* acc, uint4 v, float w) {
    unsigned u;
    u = v.x;
    acc[0] = fmaf(w, __uint_as_float(u << 16), acc[0]);
    acc[1] = fmaf(w, __uint_as_float(u & 0xffff0000u), acc[1]);
    u = v.y;
    acc[2] = fmaf(w, __uint_as_float(u << 16), acc[2]);
    acc[3] = fmaf(w, __uint_as_float(u & 0xffff0000u), acc[3]);
    u = v.z;
    acc[4] = fmaf(w, __uint_as_float(u << 16), acc[4]);
    acc[5] = fmaf(w, __uint_as_float(u & 0xffff0000u), acc[5]);
    u = v.w;
    acc[6] = fmaf(w, __uint_as_float(u << 16), acc[6]);
    acc[7] = fmaf(w, __uint_as_float(u & 0xffff0000u), acc[7]);
}

__global__ __launch_bounds__(256) void k8_agg(
        const int* __restrict__ srcs, const int* __restrict__ offs,
        const int* __restrict__ deg,
        const float* __restrict__ el, const float* __restrict__ er,
        const uint4* __restrict__ feat_v,     // bf16 rows: 64 uint4 per row
        float* __restrict__ out) {
    int lane = threadIdx.x & 63;
    int n = blockIdx.x * 4 + (threadIdx.x >> 6);   // grid 12500*4 = 50000 exact
    int start = offs[n], cnt = deg[n];
    int h = lane >> 3;
    float erh = er[(size_t)n * 8 + h];
    float acc[8] = {};
    float dsum = 0.f;

    for (int base = 0; base < cnt; base += 64) {
        int m = cnt - base; if (m > 64) m = 64;
        int s_all = (lane < m) ? srcs[start + base + lane] : 0;
        int i = 0;
        for (; i + 8 <= m; i += 8) {
            int s[8]; uint4 v[8]; float e[8];
            #pragma unroll
            for (int j = 0; j < 8; ++j) s[j] = __shfl(s_all, i + j, 64);
            #pragma unroll
            for (int j = 0; j < 8; ++j) v[j] = feat_v[(size_t)s[j] * 64 + lane];
            #pragma unroll
            for (int j = 0; j < 8; ++j) e[j] = el[(size_t)s[j] * 8 + h];
            #pragma unroll
            for (int j = 0; j < 8; ++j) {
                float x = e[j] + erh;
                x = (x >= 0.f) ? x : NEG * x;
                float w = __expf(x);
                dsum += w;
                accum8(acc, v[j], w);
            }
        }
        for (; i < m; ++i) {
            int s0 = __shfl(s_all, i, 64);
            uint4 v0 = feat_v[(size_t)s0 * 64 + lane];
            float x = el[(size_t)s0 * 8 + h] + erh;
            x = (x >= 0.f) ? x : NEG * x;
            float w = __expf(x);
            dsum += w;
            accum8(acc, v0, w);
        }
    }

    float dn = 1.f / fmaxf(dsum, 1e-16f);
    float* op = out + (size_t)n * HF + lane * 8;
    *(float4*)op       = make_float4(acc[0] * dn, acc[1] * dn, acc[2] * dn, acc[3] * dn);
    *(float4*)(op + 4) = make_float4(acc[4] * dn, acc[5] * dn, acc[6] * dn, acc[7] * dn);
}

// ---------------------------------------------------------------------------
extern "C" void kernel_launch(void* const* d_in, const int* in_sizes, int n_in,
                              void* d_out, int out_size, void* d_ws, size_t ws_size,
                              hipStream_t stream) {
    const float* feat   = (const float*)d_in[0];
    const int*   src    = (const int*)d_in[1];
    const int*   dst    = (const int*)d_in[2];
    const float* W_src  = (const float*)d_in[3];
    const float* b_src  = (const float*)d_in[4];
    const float* W_dst  = (const float*)d_in[5];
    const float* b_dst  = (const float*)d_in[6];
    const float* W_val  = (const float*)d_in[7];
    const float* b_val  = (const float*)d_in[8];
    const float* attn_l = (const float*)d_in[9];
    const float* attn_r = (const float*)d_in[10];
    float* out = (float*)d_out;

    char* ws = (char*)d_ws;
    size_t off = 0;
    auto alloc = [&](size_t bytes) -> void* {
        void* p = ws + off;
        off += (bytes + 255) & ~(size_t)255;
        return p;
    };

    unsigned short* Wt      = (unsigned short*)alloc((size_t)IN_F * HF * 2);
    unsigned short* feat_v  = (unsigned short*)alloc((size_t)N_PAD * HF * 2);
    unsigned short* w_lr    = (unsigned short*)alloc((size_t)16 * IN_F * 2);
    float* c_lr   = (float*)alloc(16 * 4);
    float* el     = (float*)alloc((size_t)N_PAD * 8 * 4);
    float* er     = (float*)alloc((size_t)N_PAD * 8 * 4);
    int*   deg    = (int*)alloc((size_t)N_NODES * 4);
    int*   offs   = (int*)alloc((size_t)N_NODES * 4);
    int*   cursor = (int*)alloc((size_t)N_NODES * 4);
    int*   srcs   = (int*)alloc((size_t)N_EDGES * 4);
    (void)ws_size; (void)in_sizes; (void)n_in; (void)out_size;

    hipMemsetAsync(deg, 0, (size_t)N_NODES * 4, stream);
    k14_misc<<<K14_BLOCKS, 256, 0, stream>>>(W_val, Wt, W_src, b_src, W_dst, b_dst,
                                             attn_l, attn_r, w_lr, c_lr, dst, deg);
    kS_scan<<<(N_NODES + 1023) / 1024, 1024, 0, stream>>>(deg, offs, cursor);
    k36_gemm_scatter<<<K36_BLOCKS, 256, 0, stream>>>(feat, Wt, w_lr, c_lr, b_val,
                                                     feat_v, el, er,
                                                     src, dst, cursor, srcs);
    k8_agg<<<N_NODES / 4, 256, 0, stream>>>(srcs, offs, deg, el, er,
                                            (const uint4*)feat_v, out);
}